// Round 8
// baseline (159.344 us; speedup 1.0000x reference)
//
#include <hip/hip_runtime.h>
#include <math.h>

#define NB 2
#define NR 16384
#define NRAY (NB*NR)   // 32768 rays
#define NS 48
#define NC 32
#define ND 64
#define RPW 4                 // rays per wave
#define NWAVE (NRAY/RPW)      // 8192 waves
#define NBLK (NWAVE/4)        // 2048 blocks of 4 waves

// d_ws layout: [0]=min bits, [1]=max bits, [2..3] pad, floats [4 .. 4+NWAVE) = per-wave var partials

__global__ void init_ws_kernel(unsigned int* ws) {
    ws[0] = 0x7f7fffffu;   // FLT_MAX bits (depths are positive)
    ws[1] = 0u;
}

__global__ void minmax_kernel(const float* __restrict__ depths, unsigned int* __restrict__ ws) {
    int ray = blockIdx.x * blockDim.x + threadIdx.x;   // 32768 threads
    float mn = depths[(size_t)ray * NS];               // sorted along S: endpoints
    float mx = depths[(size_t)ray * NS + (NS - 1)];
#pragma unroll
    for (int off = 32; off > 0; off >>= 1) {
        mn = fminf(mn, __shfl_xor(mn, off));
        mx = fmaxf(mx, __shfl_xor(mx, off));
    }
    if ((threadIdx.x & 63) == 0) {
        atomicMin(&ws[0], __float_as_uint(mn));   // uint order == float order for positive floats
        atomicMax(&ws[1], __float_as_uint(mx));   // 512 total, spread out
    }
}

__device__ __forceinline__ float4 shfl_xor4(float4 v, int m) {
    float4 r;
    r.x = __shfl_xor(v.x, m);
    r.y = __shfl_xor(v.y, m);
    r.z = __shfl_xor(v.z, m);
    r.w = __shfl_xor(v.w, m);
    return r;
}

__global__ __launch_bounds__(256) void march_kernel(
    const float* __restrict__ colors, const float* __restrict__ densities,
    const float* __restrict__ depths, const float* __restrict__ dinos,
    float* __restrict__ out, const unsigned int* __restrict__ ws_mm,
    float* __restrict__ vb)
{
    const int wid  = threadIdx.x >> 6;
    const int lane = threadIdx.x & 63;
    const int gw   = blockIdx.x * 4 + wid;        // global wave id, 0..NWAVE-1

    const float gmin = __uint_as_float(ws_mm[0]);
    const float gmax = __uint_as_float(ws_mm[1]);

    // output chunk bases (return order, flat)
    float* out_rgb = out;
    float* out_dep = out + (size_t)NRAY * NC;
    float* out_w   = out + (size_t)NRAY * (NC + 1);
    float* out_bg  = out + (size_t)NRAY * (NC + 1 + (NS - 1));
    float* out_din = out + (size_t)NRAY * (NC + 2 + (NS - 1));
    float* out_wt  = out + (size_t)NRAY * (NC + 2 + (NS - 1) + ND);

    float varacc = 0.f;

    for (int it = 0; it < RPW; ++it) {
        const int ray = gw * RPW + it;            // contiguous rays per wave

        const float* dep = depths    + (size_t)ray * NS;
        const float* den = densities + (size_t)ray * NS;

        float d_i = (lane < NS) ? dep[lane] : 0.f;
        float n_i = (lane < NS) ? den[lane] : 0.f;
        float d_n = __shfl_down(d_i, 1);
        float n_n = __shfl_down(n_i, 1);

        const bool act = (lane < NS - 1);             // 47 intervals
        float delta = d_n - d_i;
        float dm    = 0.5f * (d_i + d_n);             // depths_mid
        float x     = 0.5f * (n_i + n_n) - 1.0f;      // densities_mid - 1
        float sp    = fmaxf(x, 0.f) + log1pf(expf(-fabsf(x)));   // stable softplus
        float alpha = act ? (1.f - expf(-sp * delta)) : 0.f;
        float f     = act ? (1.f - alpha + 1e-10f) : 1.f;

        // inclusive prefix product (Kogge-Stone) over 64 lanes
        float incl = f;
#pragma unroll
        for (int off = 1; off < 64; off <<= 1) {
            float o = __shfl_up(incl, off);
            if (lane >= off) incl *= o;
        }
        float T = __shfl_up(incl, 1);
        if (lane == 0) T = 1.f;
        float w  = alpha * T;                         // lanes >= 47 have w == 0
        float bg = __shfl(incl, 45);                  // T_46 = prod_{j<=45} f_j

        // butterfly reductions: W = sum w, M = sum w*dm (all lanes get result)
        float W = w, M = w * dm;
#pragma unroll
        for (int off = 32; off > 0; off >>= 1) {
            W += __shfl_xor(W, off);
            M += __shfl_xor(M, off);
        }
        // exact two-pass variance numerator: sum w*(dm - M)^2
        float dv = dm - M;
        float vn = w * dv * dv;
#pragma unroll
        for (int off = 32; off > 0; off >>= 1) vn += __shfl_xor(vn, off);

        // coefficients v_j = 0.5*(w_{j-1} + w_j); lane j holds v_j (v_48.. = 0)
        float wprev = __shfl_up(w, 1);
        if (lane == 0) wprev = 0.f;
        float v = 0.5f * (wprev + w);

        if (act) out_w[(size_t)ray * (NS - 1) + lane] = w;

        if (lane == 0) {
            float cd = M / W;
            if (cd != cd) cd = INFINITY;              // nan_to_num(nan=inf)
            cd = fminf(fmaxf(cd, gmin), gmax);        // clip (inf -> gmax)
            out_dep[ray] = cd;
            out_bg[ray]  = bg;
            out_wt[ray]  = W;
        }
        varacc += vn / (W + 1e-6f);                   // lane-uniform

        // composite_rgb: tile t = samples 8t..8t+7; v via bpermute (no LDS)
        {
            const float4* cp = (const float4*)(colors + (size_t)ray * (NS * NC));
            const int jr = lane >> 3;
            float4 acc = make_float4(0.f, 0.f, 0.f, 0.f);
#pragma unroll
            for (int t = 0; t < NS / 8; ++t) {
                float vv = __shfl(v, 8 * t + jr);
                float4 c = cp[64 * t + lane];
                acc.x += vv * c.x; acc.y += vv * c.y; acc.z += vv * c.z; acc.w += vv * c.w;
            }
#pragma unroll
            for (int off = 8; off < 64; off <<= 1) {
                float4 o = shfl_xor4(acc, off);
                acc.x += o.x; acc.y += o.y; acc.z += o.z; acc.w += o.w;
            }
            if (lane < 8) {
                float4 r = make_float4(2.f * acc.x - 1.f, 2.f * acc.y - 1.f,
                                       2.f * acc.z - 1.f, 2.f * acc.w - 1.f);
                ((float4*)(out_rgb + (size_t)ray * NC))[lane] = r;
            }
        }

        // composite_dino: tile t = samples 4t..4t+3
        {
            const float4* dp = (const float4*)(dinos + (size_t)ray * (NS * ND));
            const int jr = lane >> 4;
            float4 acc = make_float4(0.f, 0.f, 0.f, 0.f);
#pragma unroll
            for (int t = 0; t < NS / 4; ++t) {
                float vv = __shfl(v, 4 * t + jr);
                float4 c = dp[64 * t + lane];
                acc.x += vv * c.x; acc.y += vv * c.y; acc.z += vv * c.z; acc.w += vv * c.w;
            }
#pragma unroll
            for (int off = 16; off < 64; off <<= 1) {
                float4 o = shfl_xor4(acc, off);
                acc.x += o.x; acc.y += o.y; acc.z += o.z; acc.w += o.w;
            }
            if (lane < 16) {
                float b = 1.f - 2.f * W;   // 2*(acc + 1 - W) - 1 = 2*acc + (1 - 2W)
                float4 r = make_float4(2.f * acc.x + b, 2.f * acc.y + b,
                                       2.f * acc.z + b, 2.f * acc.w + b);
                ((float4*)(out_din + (size_t)ray * ND))[lane] = r;
            }
        }
    }

    if (lane == 0) vb[gw] = varacc;                   // plain store, no atomics
}

__global__ __launch_bounds__(256) void finalize_kernel(
    const float* __restrict__ vb, float* __restrict__ out)
{
    float s = 0.f;
    for (int i = threadIdx.x; i < NWAVE; i += 256) s += vb[i];
#pragma unroll
    for (int off = 32; off > 0; off >>= 1) s += __shfl_xor(s, off);
    __shared__ float sh[4];
    if ((threadIdx.x & 63) == 0) sh[threadIdx.x >> 6] = s;
    __syncthreads();
    if (threadIdx.x == 0)
        out[(size_t)NRAY * 146] = (sh[0] + sh[1] + sh[2] + sh[3]) * (1.0f / (float)NRAY);
}

extern "C" void kernel_launch(void* const* d_in, const int* in_sizes, int n_in,
                              void* d_out, int out_size, void* d_ws, size_t ws_size,
                              hipStream_t stream) {
    const float* colors    = (const float*)d_in[0];
    const float* densities = (const float*)d_in[1];
    const float* depths    = (const float*)d_in[2];
    const float* dinos     = (const float*)d_in[3];
    float* out = (float*)d_out;
    unsigned int* ws = (unsigned int*)d_ws;
    float* vb = (float*)ws + 4;   // per-wave var partials

    hipLaunchKernelGGL(init_ws_kernel, dim3(1), dim3(1), 0, stream, ws);
    hipLaunchKernelGGL(minmax_kernel, dim3(NRAY / 256), dim3(256), 0, stream, depths, ws);
    hipLaunchKernelGGL(march_kernel, dim3(NBLK), dim3(256), 0, stream,
                       colors, densities, depths, dinos, out, ws, vb);
    hipLaunchKernelGGL(finalize_kernel, dim3(1), dim3(256), 0, stream, (const float*)vb, out);
}

// Round 9
// 132.385 us; speedup vs baseline: 1.2036x; 1.2036x over previous
//
#include <hip/hip_runtime.h>
#include <math.h>

#define NB 2
#define NR 16384
#define NRAY (NB*NR)   // 32768 rays
#define NS 48
#define NC 32
#define ND 64
#define NBLK (NRAY/4)  // 8192 march blocks

// d_ws layout (floats): [0 .. NBLK) = per-block var partials (vb)
//                       [NBLK .. 2*NBLK) = per-block depth min (bmn)
//                       [2*NBLK .. 3*NBLK) = per-block depth max (bmx)

__device__ __forceinline__ float4 shfl_xor4(float4 v, int m) {
    float4 r;
    r.x = __shfl_xor(v.x, m);
    r.y = __shfl_xor(v.y, m);
    r.z = __shfl_xor(v.z, m);
    r.w = __shfl_xor(v.w, m);
    return r;
}

__global__ __launch_bounds__(256) void march_kernel(
    const float* __restrict__ colors, const float* __restrict__ densities,
    const float* __restrict__ depths, const float* __restrict__ dinos,
    float* __restrict__ out, float* __restrict__ vb,
    float* __restrict__ bmn, float* __restrict__ bmx)
{
    const int wid  = threadIdx.x >> 6;
    const int lane = threadIdx.x & 63;
    const int ray  = blockIdx.x * 4 + wid;

    __shared__ float v_sh[4][NS];
    __shared__ float var_sh[4];
    __shared__ float mn_sh[4], mx_sh[4];

    const float* dep = depths    + (size_t)ray * NS;
    const float* den = densities + (size_t)ray * NS;

    float d_i = (lane < NS) ? dep[lane] : 0.f;
    float n_i = (lane < NS) ? den[lane] : 0.f;
    float d_n = __shfl_down(d_i, 1);
    float n_n = __shfl_down(n_i, 1);

    const bool act = (lane < NS - 1);             // 47 intervals
    float delta = d_n - d_i;
    float dm    = 0.5f * (d_i + d_n);             // depths_mid
    float x     = 0.5f * (n_i + n_n) - 1.0f;      // densities_mid - 1
    float sp    = fmaxf(x, 0.f) + log1pf(expf(-fabsf(x)));   // stable softplus
    float alpha = act ? (1.f - expf(-sp * delta)) : 0.f;
    float f     = act ? (1.f - alpha + 1e-10f) : 1.f;

    // per-ray depth min/max (depths sorted along S): endpoints
    if (lane == 0) mn_sh[wid] = d_i;
    if (lane == NS - 1) mx_sh[wid] = d_i;

    // inclusive prefix product (Kogge-Stone) over 64 lanes
    float incl = f;
#pragma unroll
    for (int off = 1; off < 64; off <<= 1) {
        float o = __shfl_up(incl, off);
        if (lane >= off) incl *= o;
    }
    float T = __shfl_up(incl, 1);
    if (lane == 0) T = 1.f;
    float w  = alpha * T;                         // lanes >= 47 have w == 0
    float bg = __shfl(incl, 45);                  // T_46 = prod_{j<=45} f_j

    // butterfly reductions: W = sum w, M = sum w*dm (all lanes get result)
    float W = w, M = w * dm;
#pragma unroll
    for (int off = 32; off > 0; off >>= 1) {
        W += __shfl_xor(W, off);
        M += __shfl_xor(M, off);
    }
    // exact two-pass variance numerator: sum w*(dm - M)^2
    float dv = dm - M;
    float vn = w * dv * dv;
#pragma unroll
    for (int off = 32; off > 0; off >>= 1) vn += __shfl_xor(vn, off);

    // coefficients v_j = 0.5*(w_{j-1} + w_j), j = 0..47 (w_{-1} = w_47 = 0)
    float wprev = __shfl_up(w, 1);
    if (lane == 0) wprev = 0.f;
    float v = 0.5f * (wprev + w);
    if (lane < NS) v_sh[wid][lane] = v;           // same-wave LDS RAW: no barrier needed

    // output chunk bases (return order, flat)
    float* out_rgb = out;
    float* out_dep = out + (size_t)NRAY * NC;
    float* out_w   = out + (size_t)NRAY * (NC + 1);
    float* out_bg  = out + (size_t)NRAY * (NC + 1 + (NS - 1));
    float* out_din = out + (size_t)NRAY * (NC + 2 + (NS - 1));
    float* out_wt  = out + (size_t)NRAY * (NC + 2 + (NS - 1) + ND);

    if (act) out_w[(size_t)ray * (NS - 1) + lane] = w;

    if (lane == 0) {
        float cd = M / W;
        if (cd != cd) cd = INFINITY;              // nan_to_num(nan=inf); clipped by post_kernel
        out_dep[ray] = cd;
        out_bg[ray]  = bg;
        out_wt[ray]  = W;
        var_sh[wid]  = vn / (W + 1e-6f);
    }

    // composite_rgb: tile t covers samples 8t..8t+7 (8 rows x 8 quads = 1024B/wave-read)
    {
        const float4* cp = (const float4*)(colors + (size_t)ray * (NS * NC));
        const int jr = lane >> 3;
        float4 acc = make_float4(0.f, 0.f, 0.f, 0.f);
#pragma unroll
        for (int t = 0; t < NS / 8; ++t) {
            float vv = v_sh[wid][8 * t + jr];
            float4 c = cp[64 * t + lane];
            acc.x += vv * c.x; acc.y += vv * c.y; acc.z += vv * c.z; acc.w += vv * c.w;
        }
#pragma unroll
        for (int off = 8; off < 64; off <<= 1) {
            float4 o = shfl_xor4(acc, off);
            acc.x += o.x; acc.y += o.y; acc.z += o.z; acc.w += o.w;
        }
        if (lane < 8) {
            float4 r = make_float4(2.f * acc.x - 1.f, 2.f * acc.y - 1.f,
                                   2.f * acc.z - 1.f, 2.f * acc.w - 1.f);
            ((float4*)(out_rgb + (size_t)ray * NC))[lane] = r;
        }
    }

    // composite_dino: tile t covers samples 4t..4t+3 (4 rows x 16 quads = 1024B/wave-read)
    {
        const float4* dp = (const float4*)(dinos + (size_t)ray * (NS * ND));
        const int jr = lane >> 4;
        float4 acc = make_float4(0.f, 0.f, 0.f, 0.f);
#pragma unroll
        for (int t = 0; t < NS / 4; ++t) {
            float vv = v_sh[wid][4 * t + jr];
            float4 c = dp[64 * t + lane];
            acc.x += vv * c.x; acc.y += vv * c.y; acc.z += vv * c.z; acc.w += vv * c.w;
        }
#pragma unroll
        for (int off = 16; off < 64; off <<= 1) {
            float4 o = shfl_xor4(acc, off);
            acc.x += o.x; acc.y += o.y; acc.z += o.z; acc.w += o.w;
        }
        if (lane < 16) {
            float b = 1.f - 2.f * W;   // 2*(acc + 1 - W) - 1 = 2*acc + (1 - 2W)
            float4 r = make_float4(2.f * acc.x + b, 2.f * acc.y + b,
                                   2.f * acc.z + b, 2.f * acc.w + b);
            ((float4*)(out_din + (size_t)ray * ND))[lane] = r;
        }
    }

    __syncthreads();
    if (threadIdx.x == 0) {
        // plain per-block stores; no atomics anywhere
        vb[blockIdx.x]  = var_sh[0] + var_sh[1] + var_sh[2] + var_sh[3];
        bmn[blockIdx.x] = fminf(fminf(mn_sh[0], mn_sh[1]), fminf(mn_sh[2], mn_sh[3]));
        bmx[blockIdx.x] = fmaxf(fmaxf(mx_sh[0], mx_sh[1]), fmaxf(mx_sh[2], mx_sh[3]));
    }
}

// 128 blocks x 256 threads: every block reduces bmn/bmx (8192 each) -> global min/max,
// clips its 256-ray slice of out_dep; block 0 also sums vb -> var mean.
__global__ __launch_bounds__(256) void post_kernel(
    const float* __restrict__ vb, const float* __restrict__ bmn,
    const float* __restrict__ bmx, float* __restrict__ out)
{
    const int tid  = threadIdx.x;
    const int lane = tid & 63;
    __shared__ float smn[4], smx[4], ssum[4];

    float mn = 3.402823466e+38f, mx = -3.402823466e+38f;
    const float4* a4 = (const float4*)bmn;   // 2048 float4
    const float4* b4 = (const float4*)bmx;
    for (int i = tid; i < NBLK / 4; i += 256) {
        float4 a = a4[i], b = b4[i];
        mn = fminf(mn, fminf(fminf(a.x, a.y), fminf(a.z, a.w)));
        mx = fmaxf(mx, fmaxf(fmaxf(b.x, b.y), fmaxf(b.z, b.w)));
    }
#pragma unroll
    for (int off = 32; off > 0; off >>= 1) {
        mn = fminf(mn, __shfl_xor(mn, off));
        mx = fmaxf(mx, __shfl_xor(mx, off));
    }
    if (lane == 0) { smn[tid >> 6] = mn; smx[tid >> 6] = mx; }
    __syncthreads();
    float gmin = fminf(fminf(smn[0], smn[1]), fminf(smn[2], smn[3]));
    float gmax = fmaxf(fmaxf(smx[0], smx[1]), fmaxf(smx[2], smx[3]));

    // clip this block's slice of composite_depth (inf -> gmax)
    float* out_dep = out + (size_t)NRAY * NC;
    int i = blockIdx.x * 256 + tid;
    float cd = out_dep[i];
    out_dep[i] = fminf(fmaxf(cd, gmin), gmax);

    if (blockIdx.x == 0) {
        float s = 0.f;
        const float4* v4 = (const float4*)vb;    // 2048 float4
        for (int i2 = tid; i2 < NBLK / 4; i2 += 256) {
            float4 v = v4[i2];
            s += (v.x + v.y) + (v.z + v.w);
        }
#pragma unroll
        for (int off = 32; off > 0; off >>= 1) s += __shfl_xor(s, off);
        if (lane == 0) ssum[tid >> 6] = s;
        __syncthreads();
        if (tid == 0)
            out[(size_t)NRAY * 146] = (ssum[0] + ssum[1] + ssum[2] + ssum[3]) * (1.0f / (float)NRAY);
    }
}

extern "C" void kernel_launch(void* const* d_in, const int* in_sizes, int n_in,
                              void* d_out, int out_size, void* d_ws, size_t ws_size,
                              hipStream_t stream) {
    const float* colors    = (const float*)d_in[0];
    const float* densities = (const float*)d_in[1];
    const float* depths    = (const float*)d_in[2];
    const float* dinos     = (const float*)d_in[3];
    float* out = (float*)d_out;
    float* vb  = (float*)d_ws;
    float* bmn = vb + NBLK;
    float* bmx = vb + 2 * NBLK;

    hipLaunchKernelGGL(march_kernel, dim3(NBLK), dim3(256), 0, stream,
                       colors, densities, depths, dinos, out, vb, bmn, bmx);
    hipLaunchKernelGGL(post_kernel, dim3(NRAY / 256), dim3(256), 0, stream,
                       (const float*)vb, (const float*)bmn, (const float*)bmx, out);
}

// Round 10
// 130.779 us; speedup vs baseline: 1.2184x; 1.0123x over previous
//
#include <hip/hip_runtime.h>
#include <math.h>

#define NB 2
#define NR 16384
#define NRAY (NB*NR)   // 32768 rays
#define NS 48
#define NC 32
#define ND 64
#define NBLK (NRAY/8)  // 4096 march blocks (4 waves x 2 rays each)

// d_ws layout (floats): [0 .. NBLK) = per-block var partials (vb)
//                       [NBLK .. 2*NBLK) = per-block depth min (bmn)
//                       [2*NBLK .. 3*NBLK) = per-block depth max (bmx)

__device__ __forceinline__ float4 shfl_xor4(float4 v, int m) {
    float4 r;
    r.x = __shfl_xor(v.x, m);
    r.y = __shfl_xor(v.y, m);
    r.z = __shfl_xor(v.z, m);
    r.w = __shfl_xor(v.w, m);
    return r;
}

__global__ __launch_bounds__(256) void march_kernel(
    const float* __restrict__ colors, const float* __restrict__ densities,
    const float* __restrict__ depths, const float* __restrict__ dinos,
    float* __restrict__ out, float* __restrict__ vb,
    float* __restrict__ bmn, float* __restrict__ bmx)
{
    const int wid  = threadIdx.x >> 6;
    const int lane = threadIdx.x & 63;
    const int ray0 = blockIdx.x * 8 + wid * 2;    // this wave: rays ray0, ray0+1

    __shared__ float v_sh[4][2][NS];
    __shared__ float var_sh[4];
    __shared__ float mn_sh[4], mx_sh[4];

    float d_i[2], n_i[2];
#pragma unroll
    for (int r = 0; r < 2; ++r) {
        const float* dep = depths    + (size_t)(ray0 + r) * NS;
        const float* den = densities + (size_t)(ray0 + r) * NS;
        d_i[r] = (lane < NS) ? dep[lane] : 0.f;
        n_i[r] = (lane < NS) ? den[lane] : 0.f;
    }

    const bool act = (lane < NS - 1);             // 47 intervals
    float w[2], W[2], M[2], vn[2], bg[2], v[2];
#pragma unroll
    for (int r = 0; r < 2; ++r) {
        float d_n = __shfl_down(d_i[r], 1);
        float n_n = __shfl_down(n_i[r], 1);
        float delta = d_n - d_i[r];
        float dm    = 0.5f * (d_i[r] + d_n);          // depths_mid
        float x     = 0.5f * (n_i[r] + n_n) - 1.0f;   // densities_mid - 1
        float sp    = fmaxf(x, 0.f) + log1pf(expf(-fabsf(x)));   // stable softplus
        float alpha = act ? (1.f - expf(-sp * delta)) : 0.f;
        float f     = act ? (1.f - alpha + 1e-10f) : 1.f;

        // inclusive prefix product (Kogge-Stone) over 64 lanes
        float incl = f;
#pragma unroll
        for (int off = 1; off < 64; off <<= 1) {
            float o = __shfl_up(incl, off);
            if (lane >= off) incl *= o;
        }
        float T = __shfl_up(incl, 1);
        if (lane == 0) T = 1.f;
        w[r]  = alpha * T;                            // lanes >= 47 have w == 0
        bg[r] = __shfl(incl, 45);                     // T_46

        // butterfly reductions: W = sum w, M = sum w*dm
        float Wr = w[r], Mr = w[r] * dm;
#pragma unroll
        for (int off = 32; off > 0; off >>= 1) {
            Wr += __shfl_xor(Wr, off);
            Mr += __shfl_xor(Mr, off);
        }
        W[r] = Wr; M[r] = Mr;
        float dv = dm - Mr;
        float vr = w[r] * dv * dv;
#pragma unroll
        for (int off = 32; off > 0; off >>= 1) vr += __shfl_xor(vr, off);
        vn[r] = vr;

        float wprev = __shfl_up(w[r], 1);
        if (lane == 0) wprev = 0.f;
        v[r] = 0.5f * (wprev + w[r]);
        if (lane < NS) v_sh[wid][r][lane] = v[r];     // same-wave LDS RAW: no barrier
    }

    // per-wave depth min/max (sorted along S): endpoints of both rays
    if (lane == 0)      mn_sh[wid] = fminf(d_i[0], d_i[1]);
    if (lane == NS - 1) mx_sh[wid] = fmaxf(d_i[0], d_i[1]);

    // output chunk bases (return order, flat)
    float* out_rgb = out;
    float* out_dep = out + (size_t)NRAY * NC;
    float* out_w   = out + (size_t)NRAY * (NC + 1);
    float* out_bg  = out + (size_t)NRAY * (NC + 1 + (NS - 1));
    float* out_din = out + (size_t)NRAY * (NC + 2 + (NS - 1));
    float* out_wt  = out + (size_t)NRAY * (NC + 2 + (NS - 1) + ND);

#pragma unroll
    for (int r = 0; r < 2; ++r) {
        const int ray = ray0 + r;
        if (act) out_w[(size_t)ray * (NS - 1) + lane] = w[r];
        if (lane == 0) {
            float cd = M[r] / W[r];
            if (cd != cd) cd = INFINITY;              // nan_to_num(nan=inf); clipped by post
            out_dep[ray] = cd;
            out_bg[ray]  = bg[r];
            out_wt[ray]  = W[r];
        }
    }
    if (lane == 0)
        var_sh[wid] = vn[0] / (W[0] + 1e-6f) + vn[1] / (W[1] + 1e-6f);

    // composite_rgb: tile t covers samples 8t..8t+7 (1024B/wave-read), both rays interleaved
    {
        const float4* cp0 = (const float4*)(colors + (size_t)ray0 * (NS * NC));
        const float4* cp1 = (const float4*)(colors + (size_t)(ray0 + 1) * (NS * NC));
        const int jr = lane >> 3;
        float4 a0 = make_float4(0.f, 0.f, 0.f, 0.f);
        float4 a1 = make_float4(0.f, 0.f, 0.f, 0.f);
#pragma unroll
        for (int t = 0; t < NS / 8; ++t) {
            float v0 = v_sh[wid][0][8 * t + jr];
            float v1 = v_sh[wid][1][8 * t + jr];
            float4 c0 = cp0[64 * t + lane];
            float4 c1 = cp1[64 * t + lane];
            a0.x += v0 * c0.x; a0.y += v0 * c0.y; a0.z += v0 * c0.z; a0.w += v0 * c0.w;
            a1.x += v1 * c1.x; a1.y += v1 * c1.y; a1.z += v1 * c1.z; a1.w += v1 * c1.w;
        }
#pragma unroll
        for (int off = 8; off < 64; off <<= 1) {
            float4 o0 = shfl_xor4(a0, off);
            float4 o1 = shfl_xor4(a1, off);
            a0.x += o0.x; a0.y += o0.y; a0.z += o0.z; a0.w += o0.w;
            a1.x += o1.x; a1.y += o1.y; a1.z += o1.z; a1.w += o1.w;
        }
        if (lane < 8) {
            float4 r0 = make_float4(2.f * a0.x - 1.f, 2.f * a0.y - 1.f,
                                    2.f * a0.z - 1.f, 2.f * a0.w - 1.f);
            ((float4*)(out_rgb + (size_t)ray0 * NC))[lane] = r0;
            float4 r1 = make_float4(2.f * a1.x - 1.f, 2.f * a1.y - 1.f,
                                    2.f * a1.z - 1.f, 2.f * a1.w - 1.f);
            ((float4*)(out_rgb + (size_t)(ray0 + 1) * NC))[lane] = r1;
        }
    }

    // composite_dino: tile t covers samples 4t..4t+3 (1024B/wave-read), both rays interleaved
    {
        const float4* dp0 = (const float4*)(dinos + (size_t)ray0 * (NS * ND));
        const float4* dp1 = (const float4*)(dinos + (size_t)(ray0 + 1) * (NS * ND));
        const int jr = lane >> 4;
        float4 a0 = make_float4(0.f, 0.f, 0.f, 0.f);
        float4 a1 = make_float4(0.f, 0.f, 0.f, 0.f);
#pragma unroll
        for (int t = 0; t < NS / 4; ++t) {
            float v0 = v_sh[wid][0][4 * t + jr];
            float v1 = v_sh[wid][1][4 * t + jr];
            float4 c0 = dp0[64 * t + lane];
            float4 c1 = dp1[64 * t + lane];
            a0.x += v0 * c0.x; a0.y += v0 * c0.y; a0.z += v0 * c0.z; a0.w += v0 * c0.w;
            a1.x += v1 * c1.x; a1.y += v1 * c1.y; a1.z += v1 * c1.z; a1.w += v1 * c1.w;
        }
#pragma unroll
        for (int off = 16; off < 64; off <<= 1) {
            float4 o0 = shfl_xor4(a0, off);
            float4 o1 = shfl_xor4(a1, off);
            a0.x += o0.x; a0.y += o0.y; a0.z += o0.z; a0.w += o0.w;
            a1.x += o1.x; a1.y += o1.y; a1.z += o1.z; a1.w += o1.w;
        }
        if (lane < 16) {
            float b0 = 1.f - 2.f * W[0];
            float4 r0 = make_float4(2.f * a0.x + b0, 2.f * a0.y + b0,
                                    2.f * a0.z + b0, 2.f * a0.w + b0);
            ((float4*)(out_din + (size_t)ray0 * ND))[lane] = r0;
            float b1 = 1.f - 2.f * W[1];
            float4 r1 = make_float4(2.f * a1.x + b1, 2.f * a1.y + b1,
                                    2.f * a1.z + b1, 2.f * a1.w + b1);
            ((float4*)(out_din + (size_t)(ray0 + 1) * ND))[lane] = r1;
        }
    }

    __syncthreads();
    if (threadIdx.x == 0) {
        // plain per-block stores; no atomics anywhere
        vb[blockIdx.x]  = var_sh[0] + var_sh[1] + var_sh[2] + var_sh[3];
        bmn[blockIdx.x] = fminf(fminf(mn_sh[0], mn_sh[1]), fminf(mn_sh[2], mn_sh[3]));
        bmx[blockIdx.x] = fmaxf(fmaxf(mx_sh[0], mx_sh[1]), fmaxf(mx_sh[2], mx_sh[3]));
    }
}

// 128 blocks x 256 threads: every block reduces bmn/bmx (4096 each) -> global min/max,
// clips its 256-ray slice of out_dep; block 0 also sums vb -> var mean.
__global__ __launch_bounds__(256) void post_kernel(
    const float* __restrict__ vb, const float* __restrict__ bmn,
    const float* __restrict__ bmx, float* __restrict__ out)
{
    const int tid  = threadIdx.x;
    const int lane = tid & 63;
    __shared__ float smn[4], smx[4], ssum[4];

    float mn = 3.402823466e+38f, mx = -3.402823466e+38f;
    const float4* a4 = (const float4*)bmn;   // 1024 float4
    const float4* b4 = (const float4*)bmx;
    for (int i = tid; i < NBLK / 4; i += 256) {
        float4 a = a4[i], b = b4[i];
        mn = fminf(mn, fminf(fminf(a.x, a.y), fminf(a.z, a.w)));
        mx = fmaxf(mx, fmaxf(fmaxf(b.x, b.y), fmaxf(b.z, b.w)));
    }
#pragma unroll
    for (int off = 32; off > 0; off >>= 1) {
        mn = fminf(mn, __shfl_xor(mn, off));
        mx = fmaxf(mx, __shfl_xor(mx, off));
    }
    if (lane == 0) { smn[tid >> 6] = mn; smx[tid >> 6] = mx; }
    __syncthreads();
    float gmin = fminf(fminf(smn[0], smn[1]), fminf(smn[2], smn[3]));
    float gmax = fmaxf(fmaxf(smx[0], smx[1]), fmaxf(smx[2], smx[3]));

    // clip this block's slice of composite_depth (inf -> gmax)
    float* out_dep = out + (size_t)NRAY * NC;
    int i = blockIdx.x * 256 + tid;
    float cd = out_dep[i];
    out_dep[i] = fminf(fmaxf(cd, gmin), gmax);

    if (blockIdx.x == 0) {
        float s = 0.f;
        const float4* v4 = (const float4*)vb;    // 1024 float4
        for (int i2 = tid; i2 < NBLK / 4; i2 += 256) {
            float4 v = v4[i2];
            s += (v.x + v.y) + (v.z + v.w);
        }
#pragma unroll
        for (int off = 32; off > 0; off >>= 1) s += __shfl_xor(s, off);
        if (lane == 0) ssum[tid >> 6] = s;
        __syncthreads();
        if (tid == 0)
            out[(size_t)NRAY * 146] = (ssum[0] + ssum[1] + ssum[2] + ssum[3]) * (1.0f / (float)NRAY);
    }
}

extern "C" void kernel_launch(void* const* d_in, const int* in_sizes, int n_in,
                              void* d_out, int out_size, void* d_ws, size_t ws_size,
                              hipStream_t stream) {
    const float* colors    = (const float*)d_in[0];
    const float* densities = (const float*)d_in[1];
    const float* depths    = (const float*)d_in[2];
    const float* dinos     = (const float*)d_in[3];
    float* out = (float*)d_out;
    float* vb  = (float*)d_ws;
    float* bmn = vb + NBLK;
    float* bmx = vb + 2 * NBLK;

    hipLaunchKernelGGL(march_kernel, dim3(NBLK), dim3(256), 0, stream,
                       colors, densities, depths, dinos, out, vb, bmn, bmx);
    hipLaunchKernelGGL(post_kernel, dim3(NRAY / 256), dim3(256), 0, stream,
                       (const float*)vb, (const float*)bmn, (const float*)bmx, out);
}